// Round 13
// baseline (402.219 us; speedup 1.0000x reference)
//
#include <hip/hip_runtime.h>

#define N_NODES 50000
#define N_EDGES 800000
#define FEA 128
#define NL 3
#define AH 512
#define NG 64
#define NBLK 196   // ceil(50000/256)

typedef short bf16x8 __attribute__((ext_vector_type(8)));
typedef float f32x4 __attribute__((ext_vector_type(4)));
typedef uint  u32x4 __attribute__((ext_vector_type(4)));

__device__ __forceinline__ ushort f2bf(float f) {   // RTN-even
    uint u = __float_as_uint(f);
    uint r = u + 0x7FFFu + ((u >> 16) & 1u);
    return (ushort)(r >> 16);
}
__device__ __forceinline__ float bf2f(ushort u) {
    return __uint_as_float((uint)u << 16);
}

// Column-sliced layouts: 8 slices of 32B (16 bf16) per row.
//  H  : 8 slices x [(N_NODES+1) rows][16 bf16]  (pad row at N_NODES)
//  Xhi/Xlo: 8 slices x [N_NODES rows][16 bf16]
#define HS16 ((size_t)(N_NODES + 1) * 16)   // ushorts per H slice
#define XS16 ((size_t)N_NODES * 16)         // ushorts per X slice

// ---------------- fused: degree+rank | x->Xcs hi/lo | convW split-T | H pad rows ----------------
#define DA 3125            // deg blocks (3125*256 = 800000 edges)
#define DB (DA + 3125)     // x conversion: 800000 half-chunks
#define DC (DB + 192)      // conv W split-transpose (3*16384)
#define DD (DC + 1)        // pad row zero
__global__ __launch_bounds__(256) void k_deg_prep(const int* __restrict__ dst,
                                                  int* __restrict__ deg,
                                                  ushort* __restrict__ rank,
                                                  const float* __restrict__ x,
                                                  ushort* __restrict__ Xhi,
                                                  ushort* __restrict__ Xlo,
                                                  const float* __restrict__ convW,
                                                  ushort* __restrict__ WhiT,
                                                  ushort* __restrict__ WloT,
                                                  ushort* __restrict__ H) {
    int blk = blockIdx.x;
    if (blk < DA) {                        // degree histogram + rank
        int i = blk * 256 + threadIdx.x;
        rank[i] = (ushort)atomicAdd(&deg[dst[i]], 1);
    } else if (blk < DB) {                 // x -> column-sliced Xhi/Xlo (8 floats/thread)
        int i = (blk - DA) * 256 + threadIdx.x;   // half-chunk id, 0..799999
        int node = i >> 4, h16 = i & 15;
        int c = h16 >> 1, half = h16 & 1;
        const float* xr = x + (size_t)node * FEA + c * 16 + half * 8;
        float4 u0 = *(const float4*)xr;
        float4 u1 = *(const float4*)(xr + 4);
        float xs[8] = {u0.x, u0.y, u0.z, u0.w, u1.x, u1.y, u1.z, u1.w};
        ushort hs[8]; uint ls[8];
#pragma unroll
        for (int k = 0; k < 8; ++k) {
            hs[k] = f2bf(xs[k]);
            ls[k] = f2bf(xs[k] - bf2f(hs[k]));
        }
        u32x4 hv, lv;
        hv.x = (uint)hs[0] | ((uint)hs[1] << 16);
        hv.y = (uint)hs[2] | ((uint)hs[3] << 16);
        hv.z = (uint)hs[4] | ((uint)hs[5] << 16);
        hv.w = (uint)hs[6] | ((uint)hs[7] << 16);
        lv.x = ls[0] | (ls[1] << 16);
        lv.y = ls[2] | (ls[3] << 16);
        lv.z = ls[4] | (ls[5] << 16);
        lv.w = ls[6] | (ls[7] << 16);
        size_t off = (size_t)c * XS16 + (size_t)node * 16 + half * 8;
        *(u32x4*)(Xhi + off) = hv;
        *(u32x4*)(Xlo + off) = lv;
    } else if (blk < DC) {                 // conv W split-transpose
        int t = (blk - DB) * 256 + threadIdx.x;     // 0..49151
        int l = t >> 14, r = t & 16383;
        int k = r >> 7, c = r & 127;
        float w = convW[t];
        ushort h = f2bf(w);
        WhiT[(size_t)l * 16384 + c * FEA + k] = h;
        WloT[(size_t)l * 16384 + c * FEA + k] = f2bf(w - bf2f(h));
    } else {                               // zero H pad rows (8 slices x 32B)
        if (threadIdx.x < 64) {
            int c = threadIdx.x >> 3, j = threadIdx.x & 7;
            ((uint*)H)[(size_t)c * (HS16 / 2) + (size_t)N_NODES * 8 + j] = 0;
        }
    }
}

// ---------------- 3-kernel exclusive scan over PADDED degrees ----------------
__device__ __forceinline__ int block_scan_incl(int v, int* wsum) {
    int lane = threadIdx.x & 63, w = threadIdx.x >> 6;
    int s = v;
#pragma unroll
    for (int off = 1; off < 64; off <<= 1) {
        int t = __shfl_up(s, off);
        if (lane >= off) s += t;
    }
    if (lane == 63) wsum[w] = s;
    __syncthreads();
    int woff = 0;
    for (int k = 0; k < w; ++k) woff += wsum[k];
    return woff + s;  // block-wide inclusive
}

__global__ __launch_bounds__(256) void k_scan1(const int* __restrict__ deg,
                                               int* __restrict__ rowptr,
                                               int* __restrict__ bsum,
                                               float* __restrict__ dinv) {
    __shared__ int wsum[4];
    int i = blockIdx.x * 256 + threadIdx.x;
    int v = (i < N_NODES) ? deg[i] : 0;
    int pv = (v + 7) & ~7;                       // pad to multiple of 8
    int incl = block_scan_incl(pv, wsum);
    if (i < N_NODES) {
        rowptr[i] = incl - pv;                   // local exclusive
        dinv[i] = rsqrtf((float)v + 1.0f);
    }
    if (threadIdx.x == 255) bsum[blockIdx.x] = incl;
}

__global__ __launch_bounds__(256) void k_scan2(int* __restrict__ bsum,
                                               int* __restrict__ boff,
                                               int* __restrict__ rowptr) {
    __shared__ int wsum[4];
    int v = (threadIdx.x < NBLK) ? bsum[threadIdx.x] : 0;
    int incl = block_scan_incl(v, wsum);
    if (threadIdx.x < NBLK) boff[threadIdx.x] = incl - v;
    if (threadIdx.x == NBLK - 1) rowptr[N_NODES] = incl;  // total padded edges
}

__global__ __launch_bounds__(256) void k_scan3(int* __restrict__ rowptr,
                                               const int* __restrict__ boff) {
    int i = blockIdx.x * 256 + threadIdx.x;
    if (i < N_NODES) rowptr[i] += boff[blockIdx.x];
}

// ---------------- fused: CSR fill | pad slots | graph bounds ----------------
#define FA 3125
#define FB (FA + NBLK)
#define FC (FB + NBLK)
__global__ __launch_bounds__(256) void k_fill2(const int* __restrict__ src,
                                               const int* __restrict__ dst,
                                               const int* __restrict__ rowptr,
                                               const ushort* __restrict__ rank,
                                               const int* __restrict__ deg,
                                               const int* __restrict__ batch,
                                               ushort* __restrict__ eidx,
                                               int* __restrict__ gstart) {
    int blk = blockIdx.x;
    if (blk < FA) {                        // CSR fill (no atomics)
        int e = blk * 256 + threadIdx.x;
        eidx[rowptr[dst[e]] + (int)rank[e]] = (ushort)src[e];
    } else if (blk < FB) {                 // pad slots -> zero row
        int i = (blk - FA) * 256 + threadIdx.x;
        if (i < N_NODES) {
            int d = deg[i], r = rowptr[i];
            int pd = (d + 7) & ~7;
            for (int k = d; k < pd; ++k) eidx[r + k] = (ushort)N_NODES;
        }
    } else {                               // graph bounds from sorted batch
        int i = (blk - FB) * 256 + threadIdx.x;
        if (i < N_NODES) {
            int b = batch[i];
            int bp = (i == 0) ? -1 : batch[i - 1];
            for (int g = bp + 1; g <= b; ++g) gstart[g] = i;
            if (i == N_NODES - 1)
                for (int g = b + 1; g <= NG; ++g) gstart[g] = N_NODES;
        }
    }
}

// ---------------- MFMA GEMM: H'cs(bf16) = dinv * (Xcs @ W) ----------------
__global__ __launch_bounds__(256) void k_gemm(const ushort* __restrict__ Xhi,
                                              const ushort* __restrict__ Xlo,
                                              const ushort* __restrict__ WhiT,
                                              const ushort* __restrict__ WloT,
                                              const float* __restrict__ dinv,
                                              ushort* __restrict__ H) {
    const int wv = threadIdx.x >> 6;
    const int lane = threadIdx.x & 63;
    const int lr = lane & 15;
    const int lk = lane >> 4;

    bf16x8 bhi[2][4], blo[2][4];
#pragma unroll
    for (int ct = 0; ct < 2; ++ct) {
        int col = wv * 32 + ct * 16 + lr;
#pragma unroll
        for (int kf = 0; kf < 4; ++kf) {
            bhi[ct][kf] = *(const bf16x8*)(WhiT + (size_t)col * FEA + kf * 32 + lk * 8);
            blo[ct][kf] = *(const bf16x8*)(WloT + (size_t)col * FEA + kf * 32 + lk * 8);
        }
    }

    for (int rt = blockIdx.x; rt < N_NODES / 16; rt += gridDim.x) {
        int r0 = rt * 16;
        bf16x8 ahi[4], alo[4];
#pragma unroll
        for (int kf = 0; kf < 4; ++kf) {
            // feature base kf*32 + lk*8 -> slice 2kf+(lk>>1), intra (lk&1)*8
            size_t ao = (size_t)(2 * kf + (lk >> 1)) * XS16 +
                        (size_t)(r0 + lr) * 16 + (lk & 1) * 8;
            ahi[kf] = *(const bf16x8*)(Xhi + ao);
            alo[kf] = *(const bf16x8*)(Xlo + ao);
        }
        f32x4 acc0 = {0.f, 0.f, 0.f, 0.f};
        f32x4 acc1 = {0.f, 0.f, 0.f, 0.f};
#pragma unroll
        for (int kf = 0; kf < 4; ++kf) {
            acc0 = __builtin_amdgcn_mfma_f32_16x16x32_bf16(ahi[kf], bhi[0][kf], acc0, 0, 0, 0);
            acc0 = __builtin_amdgcn_mfma_f32_16x16x32_bf16(ahi[kf], blo[0][kf], acc0, 0, 0, 0);
            acc0 = __builtin_amdgcn_mfma_f32_16x16x32_bf16(alo[kf], bhi[0][kf], acc0, 0, 0, 0);
            acc1 = __builtin_amdgcn_mfma_f32_16x16x32_bf16(ahi[kf], bhi[1][kf], acc1, 0, 0, 0);
            acc1 = __builtin_amdgcn_mfma_f32_16x16x32_bf16(ahi[kf], blo[1][kf], acc1, 0, 0, 0);
            acc1 = __builtin_amdgcn_mfma_f32_16x16x32_bf16(alo[kf], bhi[1][kf], acc1, 0, 0, 0);
        }
        // acc0 cols wv*32+lr -> slice 2wv, intra lr; acc1 -> slice 2wv+1, intra lr
#pragma unroll
        for (int reg = 0; reg < 4; ++reg) {
            int orow = r0 + lk * 4 + reg;
            float s = dinv[orow];
            H[(size_t)(2 * wv) * HS16 + (size_t)orow * 16 + lr]     = f2bf(acc0[reg] * s);
            H[(size_t)(2 * wv + 1) * HS16 + (size_t)orow * 16 + lr] = f2bf(acc1[reg] * s);
        }
    }
}

// ---------------- gather: wave-per-node, 8 edges x 8 uint-lanes ----------------
// c = blk&7 -> 1:1 slice:XCD; per-XCD L2 WS = slice(1.6MB)+eidx(1.6MB).
#define GNPB 64    // nodes per block
#define GNT ((N_NODES + GNPB - 1) / GNPB)
__global__ __launch_bounds__(256) void k_gather(const int* __restrict__ rowptr,
                                                const ushort* __restrict__ eidx,
                                                const float* __restrict__ dinv,
                                                const ushort* __restrict__ H,
                                                const float* __restrict__ b,
                                                ushort* __restrict__ Xhi,
                                                ushort* __restrict__ Xlo) {
    int c = blockIdx.x & 7;
    int base = (blockIdx.x >> 3) * GNPB;
    int wv = threadIdx.x >> 6;
    int lane = threadIdx.x & 63;
    int eg = lane >> 3;      // edge group 0..7
    int fo = lane & 7;       // uint offset in 32B slice row
    const uint* Hu = (const uint*)H + (size_t)c * (HS16 / 2);
    uint* Xh = (uint*)Xhi + (size_t)c * (XS16 / 2);
    uint* Xl = (uint*)Xlo + (size_t)c * (XS16 / 2);
    float2 bb = *(const float2*)(b + c * 16 + fo * 2);

    int nend = min(base + GNPB, N_NODES);
    for (int node = base + wv; node < nend; node += 4) {
        int r0 = rowptr[node], r1 = rowptr[node + 1];
        float2 a0 = {0.f, 0.f}, a1 = {0.f, 0.f};
        int j = r0;
        for (; j + 16 <= r1; j += 16) {
            int e0 = eidx[j + eg];
            int e1 = eidx[j + 8 + eg];
            uint v0 = Hu[(size_t)e0 * 8 + fo];
            uint v1 = Hu[(size_t)e1 * 8 + fo];
            a0.x += bf2f((ushort)v0); a0.y += bf2f((ushort)(v0 >> 16));
            a1.x += bf2f((ushort)v1); a1.y += bf2f((ushort)(v1 >> 16));
        }
        if (j < r1) {
            int e0 = eidx[j + eg];
            uint v0 = Hu[(size_t)e0 * 8 + fo];
            a0.x += bf2f((ushort)v0); a0.y += bf2f((ushort)(v0 >> 16));
        }
        a0.x += a1.x; a0.y += a1.y;
        // reduce across edge groups (same fo): strides 8,16,32
        a0.x += __shfl_xor(a0.x, 8);  a0.y += __shfl_xor(a0.y, 8);
        a0.x += __shfl_xor(a0.x, 16); a0.y += __shfl_xor(a0.y, 16);
        a0.x += __shfl_xor(a0.x, 32); a0.y += __shfl_xor(a0.y, 32);
        // self term (all lanes, per-fo)
        uint sv = Hu[(size_t)node * 8 + fo];
        a0.x += bf2f((ushort)sv); a0.y += bf2f((ushort)(sv >> 16));
        float di = dinv[node];
        float ox = fmaxf(a0.x * di + bb.x, 0.f);
        float oy = fmaxf(a0.y * di + bb.y, 0.f);
        ushort hx = f2bf(ox), hy = f2bf(oy);
        uint hv = (uint)hx | ((uint)hy << 16);
        uint lv = (uint)f2bf(ox - bf2f(hx)) | ((uint)f2bf(oy - bf2f(hy)) << 16);
        if (eg == 0) Xh[(size_t)node * 8 + fo] = hv;
        else if (eg == 1) Xl[(size_t)node * 8 + fo] = lv;
    }
}

// ---------------- pool + node head (no atomics), 16 partials/graph ----------------
__global__ __launch_bounds__(256) void k_pool(const ushort* __restrict__ Xhi,
                                              const ushort* __restrict__ Xlo,
                                              const int* __restrict__ gstart,
                                              const float* __restrict__ nw,
                                              const float* __restrict__ nbp,
                                              float* __restrict__ out_node,
                                              float* __restrict__ psum_part) {
    int g = blockIdx.x >> 4, p = blockIdx.x & 15;
    int s = gstart[g], e = gstart[g + 1];
    int len = e - s;
    int lp = (len + 15) >> 4;
    int ps = s + p * lp, pe = min(ps + lp, e);
    int q = threadIdx.x >> 6, lane = threadIdx.x & 63;
    // lane l holds features 2l,2l+1: uint index l -> slice l>>3, intra l&7
    const uint* hb = (const uint*)Xhi + (size_t)(lane >> 3) * (XS16 / 2) + (lane & 7);
    const uint* lb = (const uint*)Xlo + (size_t)(lane >> 3) * (XS16 / 2) + (lane & 7);
    float2 w = ((const float2*)nw)[lane];
    float nbv = nbp[0];
    float2 acc = {0.f, 0.f};
    for (int node = ps + q; node < pe; node += 4) {
        uint hv = hb[(size_t)node * 8];
        uint lv = lb[(size_t)node * 8];
        float2 v;
        v.x = bf2f((ushort)hv) + bf2f((ushort)lv);
        v.y = bf2f((ushort)(hv >> 16)) + bf2f((ushort)(lv >> 16));
        acc.x += v.x; acc.y += v.y;
        float dot = v.x * w.x + v.y * w.y;
#pragma unroll
        for (int off = 32; off; off >>= 1) dot += __shfl_down(dot, off);
        if (lane == 0) out_node[node] = dot + nbv;
    }
    __shared__ float lds[4 * FEA];
    lds[q * FEA + lane * 2 + 0] = acc.x;
    lds[q * FEA + lane * 2 + 1] = acc.y;
    __syncthreads();
    if (threadIdx.x < FEA) {
        psum_part[(size_t)blockIdx.x * FEA + threadIdx.x] =
            lds[threadIdx.x] + lds[FEA + threadIdx.x] +
            lds[2 * FEA + threadIdx.x] + lds[3 * FEA + threadIdx.x];
    }
}

// ---------------- MLP layer 1 (direct strided w1 reads) ----------------
__global__ __launch_bounds__(256) void k_mlp1(const float* __restrict__ psum_part,
                                              const int* __restrict__ gstart,
                                              const float* __restrict__ w1,
                                              const float* __restrict__ b1,
                                              float* __restrict__ h1ws) {
    __shared__ float feas[NG * 132];   // pad 132 to spread banks
    for (int idx = threadIdx.x; idx < NG * FEA; idx += 256) {
        int g = idx >> 7, f = idx & 127;
        const float* pp = psum_part + (size_t)g * 16 * FEA + f;
        float sum = 0.f;
#pragma unroll
        for (int p = 0; p < 16; ++p) sum += pp[p * FEA];
        float cnt = fmaxf((float)(gstart[g + 1] - gstart[g]), 1.0f);
        feas[g * 132 + f] = sum / cnt;
    }
    __syncthreads();
    int g = threadIdx.x >> 2, jj = threadIdx.x & 3;
    int j = blockIdx.x * 4 + jj;
    const float* fr = feas + g * 132;
    float a0 = 0.f, a1 = 0.f, a2 = 0.f, a3 = 0.f;
#pragma unroll 8
    for (int k = 0; k < FEA; k += 4) {
        a0 += fr[k + 0] * w1[(k + 0) * AH + j];
        a1 += fr[k + 1] * w1[(k + 1) * AH + j];
        a2 += fr[k + 2] * w1[(k + 2) * AH + j];
        a3 += fr[k + 3] * w1[(k + 3) * AH + j];
    }
    h1ws[(size_t)g * AH + j] = fmaxf((a0 + a1) + (a2 + a3) + b1[j], 0.f);
}

// ---------------- MLP layer 2 (direct strided w2 reads) ----------------
__global__ __launch_bounds__(256) void k_mlp2(const float* __restrict__ h1ws,
                                              const float* __restrict__ w2,
                                              const float* __restrict__ b2,
                                              float* __restrict__ out_fea) {
    int f = blockIdx.x;
    int g = threadIdx.x >> 2, q = threadIdx.x & 3;
    const float* hr = h1ws + (size_t)g * AH + q * 128;
    const float* wr = w2 + (size_t)q * 128 * FEA + f;
    float a0 = 0.f, a1 = 0.f, a2 = 0.f, a3 = 0.f;
#pragma unroll 8
    for (int k = 0; k < 128; k += 4) {
        a0 += hr[k + 0] * wr[(k + 0) * FEA];
        a1 += hr[k + 1] * wr[(k + 1) * FEA];
        a2 += hr[k + 2] * wr[(k + 2) * FEA];
        a3 += hr[k + 3] * wr[(k + 3) * FEA];
    }
    float p = (a0 + a1) + (a2 + a3);
    p += __shfl_xor(p, 1);
    p += __shfl_xor(p, 2);
    if (q == 0) out_fea[(size_t)g * FEA + f] = p + b2[f];
}

extern "C" void kernel_launch(void* const* d_in, const int* in_sizes, int n_in,
                              void* d_out, int out_size, void* d_ws, size_t ws_size,
                              hipStream_t stream) {
    const float* x     = (const float*)d_in[0];
    const int*   ei    = (const int*)d_in[1];
    const int*   batch = (const int*)d_in[2];
    const float* convW = (const float*)d_in[3];
    const float* convb = (const float*)d_in[4];
    const float* w1    = (const float*)d_in[5];
    const float* b1    = (const float*)d_in[6];
    const float* w2    = (const float*)d_in[7];
    const float* b2    = (const float*)d_in[8];
    const float* nw    = (const float*)d_in[9];
    const float* nb    = (const float*)d_in[10];
    float* out = (float*)d_out;

    // workspace layout (4-byte word offsets)
    char* wsb = (char*)d_ws;
    int*    deg    = (int*)wsb;                        // 50000
    float*  dinv   = (float*)(wsb + 50048ll * 4);      // 50000
    int*    rowptr = (int*)(wsb + 100096ll * 4);       // 50001
    int*    bsum   = (int*)(wsb + 150144ll * 4);       // 196
    int*    boff   = (int*)(wsb + 150344ll * 4);       // 196
    int*    gstart = (int*)(wsb + 150544ll * 4);       // 65
    int*    rankw  = (int*)(wsb + 150656ll * 4);       // 400000 words
    ushort* rank   = (ushort*)rankw;                   // 800000 ushort
    float*  h1ws   = (float*)rankw;                    // 32768 w (after fill)
    ushort* eidx   = (ushort*)(wsb + 950656ll * 4);    // <=1.3M ushort
    ushort* H      = (ushort*)(wsb + 1600672ll * 4);   // 8*(N+1)*16 bf16
    ushort* Xhi    = (ushort*)(wsb + 4800736ll * 4);   // 8*N*16 bf16
    ushort* Xlo    = (ushort*)(wsb + 8000736ll * 4);   // 8*N*16 bf16
    float*  psum_part = (float*)(wsb + 11200736ll * 4);// 1024*128 floats
    // WhiT/WloT alias psum_part: dead after last gemm, psum written by k_pool later
    ushort* WhiT   = (ushort*)psum_part;               // 49152 shorts
    ushort* WloT   = WhiT + 49152;                     // 49152 shorts

    const int* srcp = ei;
    const int* dstp = ei + N_EDGES;

    // ---- CSR build + prep ----
    hipMemsetAsync(deg, 0, N_NODES * sizeof(int), stream);
    k_deg_prep<<<DD, 256, 0, stream>>>(dstp, deg, rank, x, Xhi, Xlo, convW, WhiT, WloT, H);
    k_scan1<<<NBLK, 256, 0, stream>>>(deg, rowptr, bsum, dinv);
    k_scan2<<<1, 256, 0, stream>>>(bsum, boff, rowptr);
    k_scan3<<<NBLK, 256, 0, stream>>>(rowptr, boff);
    k_fill2<<<FC, 256, 0, stream>>>(srcp, dstp, rowptr, rank, deg, batch, eidx, gstart);

    // ---- GCN layers ----
    for (int l = 0; l < NL; ++l) {
        k_gemm<<<1024, 256, 0, stream>>>(Xhi, Xlo, WhiT + (size_t)l * 16384,
                                         WloT + (size_t)l * 16384, dinv, H);
        k_gather<<<GNT * 8, 256, 0, stream>>>(
            rowptr, eidx, dinv, H, convb + (size_t)l * FEA, Xhi, Xlo);
    }

    // ---- heads ----
    k_pool<<<NG * 16, 256, 0, stream>>>(Xhi, Xlo, gstart, nw, nb, out, psum_part);
    k_mlp1<<<128, 256, 0, stream>>>(psum_part, gstart, w1, b1, h1ws);
    k_mlp2<<<128, 256, 0, stream>>>(h1ws, w2, b2, out + N_NODES);
}

// Round 14
// 246.859 us; speedup vs baseline: 1.6293x; 1.6293x over previous
//
#include <hip/hip_runtime.h>

#define N_NODES 50000
#define N_EDGES 800000
#define FEA 128
#define NL 3
#define AH 512
#define NG 64
#define NBLK 196   // ceil(50000/256)

typedef short bf16x8 __attribute__((ext_vector_type(8)));
typedef float f32x4 __attribute__((ext_vector_type(4)));
typedef uint  u32x4 __attribute__((ext_vector_type(4)));

__device__ __forceinline__ ushort f2bf(float f) {   // RTN-even
    uint u = __float_as_uint(f);
    uint r = u + 0x7FFFu + ((u >> 16) & 1u);
    return (ushort)(r >> 16);
}
__device__ __forceinline__ float bf2f(ushort u) {
    return __uint_as_float((uint)u << 16);
}

// Column-sliced layouts: 4 slices of 64B (32 bf16 features) per row.
//  H  : 4 slices x [(N_NODES+1) rows][32 bf16]  (pad row at N_NODES)
//  Xhi/Xlo: 4 slices x [N_NODES rows][32 bf16]
#define HS ((size_t)(N_NODES + 1) * 32)   // ushorts per H slice
#define XS ((size_t)N_NODES * 32)         // ushorts per X slice

// ---------------- fused: degree+rank | x->Xcs hi/lo | convW split-T | H pad rows ----------------
#define DA 3125            // deg blocks (3125*256 = 800000 edges)
#define DB (DA + 3125)     // x conversion: 800000 8-feature chunks
#define DC (DB + 192)      // conv W split-transpose (3*16384)
#define DD (DC + 1)        // pad row zero
__global__ __launch_bounds__(256) void k_deg_prep(const int* __restrict__ dst,
                                                  int* __restrict__ deg,
                                                  ushort* __restrict__ rank,
                                                  const float* __restrict__ x,
                                                  ushort* __restrict__ Xhi,
                                                  ushort* __restrict__ Xlo,
                                                  const float* __restrict__ convW,
                                                  ushort* __restrict__ WhiT,
                                                  ushort* __restrict__ WloT,
                                                  ushort* __restrict__ H) {
    int blk = blockIdx.x;
    if (blk < DA) {                        // degree histogram + rank
        int i = blk * 256 + threadIdx.x;
        rank[i] = (ushort)atomicAdd(&deg[dst[i]], 1);
    } else if (blk < DB) {                 // x -> column-sliced Xhi/Xlo (8 floats/thread)
        int i = (blk - DA) * 256 + threadIdx.x;   // chunk id, 0..799999
        int node = i >> 4, c8 = i & 15;           // features c8*8 .. c8*8+7
        const float* xr = x + (size_t)node * FEA + c8 * 8;
        float4 u0 = *(const float4*)xr;
        float4 u1 = *(const float4*)(xr + 4);
        float xs[8] = {u0.x, u0.y, u0.z, u0.w, u1.x, u1.y, u1.z, u1.w};
        ushort hs[8]; uint ls[8];
#pragma unroll
        for (int k = 0; k < 8; ++k) {
            hs[k] = f2bf(xs[k]);
            ls[k] = f2bf(xs[k] - bf2f(hs[k]));
        }
        u32x4 hv, lv;
        hv.x = (uint)hs[0] | ((uint)hs[1] << 16);
        hv.y = (uint)hs[2] | ((uint)hs[3] << 16);
        hv.z = (uint)hs[4] | ((uint)hs[5] << 16);
        hv.w = (uint)hs[6] | ((uint)hs[7] << 16);
        lv.x = ls[0] | (ls[1] << 16);
        lv.y = ls[2] | (ls[3] << 16);
        lv.z = ls[4] | (ls[5] << 16);
        lv.w = ls[6] | (ls[7] << 16);
        size_t off = (size_t)(c8 >> 2) * XS + (size_t)node * 32 + (c8 & 3) * 8;
        *(u32x4*)(Xhi + off) = hv;
        *(u32x4*)(Xlo + off) = lv;
    } else if (blk < DC) {                 // conv W split-transpose
        int t = (blk - DB) * 256 + threadIdx.x;     // 0..49151
        int l = t >> 14, r = t & 16383;
        int k = r >> 7, c = r & 127;
        float w = convW[t];
        ushort h = f2bf(w);
        WhiT[(size_t)l * 16384 + c * FEA + k] = h;
        WloT[(size_t)l * 16384 + c * FEA + k] = f2bf(w - bf2f(h));
    } else {                               // zero H pad rows (4 slices x 64B)
        if (threadIdx.x < 64) {
            int c = threadIdx.x >> 4, j = threadIdx.x & 15;
            ((uint*)H)[(size_t)c * (HS / 2) + (size_t)N_NODES * 16 + j] = 0;
        }
    }
}

// ---------------- 3-kernel exclusive scan over PADDED degrees ----------------
__device__ __forceinline__ int block_scan_incl(int v, int* wsum) {
    int lane = threadIdx.x & 63, w = threadIdx.x >> 6;
    int s = v;
#pragma unroll
    for (int off = 1; off < 64; off <<= 1) {
        int t = __shfl_up(s, off);
        if (lane >= off) s += t;
    }
    if (lane == 63) wsum[w] = s;
    __syncthreads();
    int woff = 0;
    for (int k = 0; k < w; ++k) woff += wsum[k];
    return woff + s;  // block-wide inclusive
}

__global__ __launch_bounds__(256) void k_scan1(const int* __restrict__ deg,
                                               int* __restrict__ rowptr,
                                               int* __restrict__ bsum,
                                               float* __restrict__ dinv) {
    __shared__ int wsum[4];
    int i = blockIdx.x * 256 + threadIdx.x;
    int v = (i < N_NODES) ? deg[i] : 0;
    int pv = (v + 7) & ~7;                       // pad to multiple of 8
    int incl = block_scan_incl(pv, wsum);
    if (i < N_NODES) {
        rowptr[i] = incl - pv;                   // local exclusive
        dinv[i] = rsqrtf((float)v + 1.0f);
    }
    if (threadIdx.x == 255) bsum[blockIdx.x] = incl;
}

__global__ __launch_bounds__(256) void k_scan2(int* __restrict__ bsum,
                                               int* __restrict__ boff,
                                               int* __restrict__ rowptr) {
    __shared__ int wsum[4];
    int v = (threadIdx.x < NBLK) ? bsum[threadIdx.x] : 0;
    int incl = block_scan_incl(v, wsum);
    if (threadIdx.x < NBLK) boff[threadIdx.x] = incl - v;
    if (threadIdx.x == NBLK - 1) rowptr[N_NODES] = incl;  // total padded edges
}

__global__ __launch_bounds__(256) void k_scan3(int* __restrict__ rowptr,
                                               const int* __restrict__ boff) {
    int i = blockIdx.x * 256 + threadIdx.x;
    if (i < N_NODES) rowptr[i] += boff[blockIdx.x];
}

// ---------------- fused: CSR fill | pad slots | graph bounds ----------------
#define FA 3125
#define FB (FA + NBLK)
#define FC (FB + NBLK)
__global__ __launch_bounds__(256) void k_fill2(const int* __restrict__ src,
                                               const int* __restrict__ dst,
                                               const int* __restrict__ rowptr,
                                               const ushort* __restrict__ rank,
                                               const int* __restrict__ deg,
                                               const int* __restrict__ batch,
                                               ushort* __restrict__ eidx,
                                               int* __restrict__ gstart) {
    int blk = blockIdx.x;
    if (blk < FA) {                        // CSR fill (no atomics)
        int e = blk * 256 + threadIdx.x;
        eidx[rowptr[dst[e]] + (int)rank[e]] = (ushort)src[e];
    } else if (blk < FB) {                 // pad slots -> zero row
        int i = (blk - FA) * 256 + threadIdx.x;
        if (i < N_NODES) {
            int d = deg[i], r = rowptr[i];
            int pd = (d + 7) & ~7;
            for (int k = d; k < pd; ++k) eidx[r + k] = (ushort)N_NODES;
        }
    } else {                               // graph bounds from sorted batch
        int i = (blk - FB) * 256 + threadIdx.x;
        if (i < N_NODES) {
            int b = batch[i];
            int bp = (i == 0) ? -1 : batch[i - 1];
            for (int g = bp + 1; g <= b; ++g) gstart[g] = i;
            if (i == N_NODES - 1)
                for (int g = b + 1; g <= NG; ++g) gstart[g] = N_NODES;
        }
    }
}

// ---------------- MFMA GEMM: H'cs(bf16) = dinv * (Xcs @ W) ----------------
__global__ __launch_bounds__(256) void k_gemm(const ushort* __restrict__ Xhi,
                                              const ushort* __restrict__ Xlo,
                                              const ushort* __restrict__ WhiT,
                                              const ushort* __restrict__ WloT,
                                              const float* __restrict__ dinv,
                                              ushort* __restrict__ H) {
    const int wv = threadIdx.x >> 6;
    const int lane = threadIdx.x & 63;
    const int lr = lane & 15;
    const int lk = lane >> 4;

    bf16x8 bhi[2][4], blo[2][4];
#pragma unroll
    for (int ct = 0; ct < 2; ++ct) {
        int col = wv * 32 + ct * 16 + lr;
#pragma unroll
        for (int kf = 0; kf < 4; ++kf) {
            bhi[ct][kf] = *(const bf16x8*)(WhiT + (size_t)col * FEA + kf * 32 + lk * 8);
            blo[ct][kf] = *(const bf16x8*)(WloT + (size_t)col * FEA + kf * 32 + lk * 8);
        }
    }

    for (int rt = blockIdx.x; rt < N_NODES / 16; rt += gridDim.x) {
        int r0 = rt * 16;
        bf16x8 ahi[4], alo[4];
#pragma unroll
        for (int kf = 0; kf < 4; ++kf) {
            // features kf*32 + lk*8 -> slice kf, intra lk*8
            size_t ao = (size_t)kf * XS + (size_t)(r0 + lr) * 32 + lk * 8;
            ahi[kf] = *(const bf16x8*)(Xhi + ao);
            alo[kf] = *(const bf16x8*)(Xlo + ao);
        }
        f32x4 acc0 = {0.f, 0.f, 0.f, 0.f};
        f32x4 acc1 = {0.f, 0.f, 0.f, 0.f};
#pragma unroll
        for (int kf = 0; kf < 4; ++kf) {
            acc0 = __builtin_amdgcn_mfma_f32_16x16x32_bf16(ahi[kf], bhi[0][kf], acc0, 0, 0, 0);
            acc0 = __builtin_amdgcn_mfma_f32_16x16x32_bf16(ahi[kf], blo[0][kf], acc0, 0, 0, 0);
            acc0 = __builtin_amdgcn_mfma_f32_16x16x32_bf16(alo[kf], bhi[0][kf], acc0, 0, 0, 0);
            acc1 = __builtin_amdgcn_mfma_f32_16x16x32_bf16(ahi[kf], bhi[1][kf], acc1, 0, 0, 0);
            acc1 = __builtin_amdgcn_mfma_f32_16x16x32_bf16(ahi[kf], blo[1][kf], acc1, 0, 0, 0);
            acc1 = __builtin_amdgcn_mfma_f32_16x16x32_bf16(alo[kf], bhi[1][kf], acc1, 0, 0, 0);
        }
        // cols wv*32 + lr (acc0) and wv*32 + 16 + lr (acc1) -> slice wv
#pragma unroll
        for (int reg = 0; reg < 4; ++reg) {
            int orow = r0 + lk * 4 + reg;
            float s = dinv[orow];
            H[(size_t)wv * HS + (size_t)orow * 32 + lr]      = f2bf(acc0[reg] * s);
            H[(size_t)wv * HS + (size_t)orow * 32 + 16 + lr] = f2bf(acc1[reg] * s);
        }
    }
}

// ---------------- gather: 4 lanes/node x one 64B slice; c = blk&3 -> XCD-local ----------------
#define GNPB 64    // nodes per block
#define GNB ((N_NODES + GNPB - 1) / GNPB)
__global__ __launch_bounds__(256) void k_gather(const int* __restrict__ rowptr,
                                                const ushort* __restrict__ eidx,
                                                const float* __restrict__ dinv,
                                                const ushort* __restrict__ H,
                                                const float* __restrict__ b,
                                                ushort* __restrict__ Xhi,
                                                ushort* __restrict__ Xlo) {
    int c = blockIdx.x & 3;
    int node = (blockIdx.x >> 2) * GNPB + (threadIdx.x >> 2);
    int l4 = threadIdx.x & 3;              // uint4 offset within 64B slice row
    if (node >= N_NODES) return;
    const uint4* Hs = (const uint4*)H + (size_t)c * (N_NODES + 1) * 4;
    int r0 = rowptr[node], r1 = rowptr[node + 1];

    float a[8] = {0.f, 0.f, 0.f, 0.f, 0.f, 0.f, 0.f, 0.f};
#define ACC8(u)                                                              \
    do {                                                                     \
        a[0] += __uint_as_float((u).x << 16);                                \
        a[1] += __uint_as_float((u).x & 0xffff0000u);                        \
        a[2] += __uint_as_float((u).y << 16);                                \
        a[3] += __uint_as_float((u).y & 0xffff0000u);                        \
        a[4] += __uint_as_float((u).z << 16);                                \
        a[5] += __uint_as_float((u).z & 0xffff0000u);                        \
        a[6] += __uint_as_float((u).w << 16);                                \
        a[7] += __uint_as_float((u).w & 0xffff0000u);                        \
    } while (0)

    uint4 sv = Hs[(size_t)node * 4 + l4];  // self term
    ACC8(sv);

    for (int j = r0; j < r1; j += 8) {     // j 8-aligned -> 16B-aligned
        uint4 ev = *(const uint4*)(eidx + j);   // same addr across node's 4 lanes
        int s0 = ev.x & 0xffff, s1 = ev.x >> 16;
        int s2 = ev.y & 0xffff, s3 = ev.y >> 16;
        int s4 = ev.z & 0xffff, s5 = ev.z >> 16;
        int s6 = ev.w & 0xffff, s7 = ev.w >> 16;
        uint4 h0 = Hs[(size_t)s0 * 4 + l4];
        uint4 h1 = Hs[(size_t)s1 * 4 + l4];
        uint4 h2 = Hs[(size_t)s2 * 4 + l4];
        uint4 h3 = Hs[(size_t)s3 * 4 + l4];
        uint4 h4 = Hs[(size_t)s4 * 4 + l4];
        uint4 h5 = Hs[(size_t)s5 * 4 + l4];
        uint4 h6 = Hs[(size_t)s6 * 4 + l4];
        uint4 h7 = Hs[(size_t)s7 * 4 + l4];
        ACC8(h0); ACC8(h1); ACC8(h2); ACC8(h3);
        ACC8(h4); ACC8(h5); ACC8(h6); ACC8(h7);
    }
#undef ACC8

    float di = dinv[node];
    const float4* b4 = (const float4*)(b + c * 32 + l4 * 8);
    float4 bb0 = b4[0], bb1 = b4[1];
    float o[8];
    o[0] = fmaxf(a[0] * di + bb0.x, 0.f);
    o[1] = fmaxf(a[1] * di + bb0.y, 0.f);
    o[2] = fmaxf(a[2] * di + bb0.z, 0.f);
    o[3] = fmaxf(a[3] * di + bb0.w, 0.f);
    o[4] = fmaxf(a[4] * di + bb1.x, 0.f);
    o[5] = fmaxf(a[5] * di + bb1.y, 0.f);
    o[6] = fmaxf(a[6] * di + bb1.z, 0.f);
    o[7] = fmaxf(a[7] * di + bb1.w, 0.f);

    ushort hs[8];
    uint ls[8];
#pragma unroll
    for (int i = 0; i < 8; ++i) {
        hs[i] = f2bf(o[i]);
        ls[i] = f2bf(o[i] - bf2f(hs[i]));
    }
    u32x4 hv, lv;
    hv.x = (uint)hs[0] | ((uint)hs[1] << 16);
    hv.y = (uint)hs[2] | ((uint)hs[3] << 16);
    hv.z = (uint)hs[4] | ((uint)hs[5] << 16);
    hv.w = (uint)hs[6] | ((uint)hs[7] << 16);
    lv.x = ls[0] | (ls[1] << 16);
    lv.y = ls[2] | (ls[3] << 16);
    lv.z = ls[4] | (ls[5] << 16);
    lv.w = ls[6] | (ls[7] << 16);
    size_t off = (size_t)c * XS + (size_t)node * 32 + l4 * 8;
    __builtin_nontemporal_store(hv, (u32x4*)(Xhi + off));
    __builtin_nontemporal_store(lv, (u32x4*)(Xlo + off));
}

// ---------------- pool + node head (no atomics), 16 partials/graph ----------------
__global__ __launch_bounds__(256) void k_pool(const ushort* __restrict__ Xhi,
                                              const ushort* __restrict__ Xlo,
                                              const int* __restrict__ gstart,
                                              const float* __restrict__ nw,
                                              const float* __restrict__ nbp,
                                              float* __restrict__ out_node,
                                              float* __restrict__ psum_part) {
    int g = blockIdx.x >> 4, p = blockIdx.x & 15;
    int s = gstart[g], e = gstart[g + 1];
    int len = e - s;
    int lp = (len + 15) >> 4;
    int ps = s + p * lp, pe = min(ps + lp, e);
    int q = threadIdx.x >> 6, lane = threadIdx.x & 63;
    // lane l holds features 2l,2l+1: uint idx l -> slice l>>4, intra l&15
    const uint* hb = (const uint*)Xhi + (size_t)(lane >> 4) * (XS / 2) + (lane & 15);
    const uint* lb = (const uint*)Xlo + (size_t)(lane >> 4) * (XS / 2) + (lane & 15);
    float2 w = ((const float2*)nw)[lane];
    float nbv = nbp[0];
    float2 acc = {0.f, 0.f};
    for (int node = ps + q; node < pe; node += 4) {
        uint hv = hb[(size_t)node * 16];
        uint lv = lb[(size_t)node * 16];
        float2 v;
        v.x = bf2f((ushort)hv) + bf2f((ushort)lv);
        v.y = bf2f((ushort)(hv >> 16)) + bf2f((ushort)(lv >> 16));
        acc.x += v.x; acc.y += v.y;
        float dot = v.x * w.x + v.y * w.y;
#pragma unroll
        for (int off = 32; off; off >>= 1) dot += __shfl_down(dot, off);
        if (lane == 0) out_node[node] = dot + nbv;
    }
    __shared__ float lds[4 * FEA];
    lds[q * FEA + lane * 2 + 0] = acc.x;
    lds[q * FEA + lane * 2 + 1] = acc.y;
    __syncthreads();
    if (threadIdx.x < FEA) {
        psum_part[(size_t)blockIdx.x * FEA + threadIdx.x] =
            lds[threadIdx.x] + lds[FEA + threadIdx.x] +
            lds[2 * FEA + threadIdx.x] + lds[3 * FEA + threadIdx.x];
    }
}

// ---------------- MLP layer 1 (direct strided w1 reads) ----------------
__global__ __launch_bounds__(256) void k_mlp1(const float* __restrict__ psum_part,
                                              const int* __restrict__ gstart,
                                              const float* __restrict__ w1,
                                              const float* __restrict__ b1,
                                              float* __restrict__ h1ws) {
    __shared__ float feas[NG * 132];   // pad 132 to spread banks
    for (int idx = threadIdx.x; idx < NG * FEA; idx += 256) {
        int g = idx >> 7, f = idx & 127;
        const float* pp = psum_part + (size_t)g * 16 * FEA + f;
        float sum = 0.f;
#pragma unroll
        for (int p = 0; p < 16; ++p) sum += pp[p * FEA];
        float cnt = fmaxf((float)(gstart[g + 1] - gstart[g]), 1.0f);
        feas[g * 132 + f] = sum / cnt;
    }
    __syncthreads();
    int g = threadIdx.x >> 2, jj = threadIdx.x & 3;
    int j = blockIdx.x * 4 + jj;
    const float* fr = feas + g * 132;
    float a0 = 0.f, a1 = 0.f, a2 = 0.f, a3 = 0.f;
#pragma unroll 8
    for (int k = 0; k < FEA; k += 4) {
        a0 += fr[k + 0] * w1[(k + 0) * AH + j];
        a1 += fr[k + 1] * w1[(k + 1) * AH + j];
        a2 += fr[k + 2] * w1[(k + 2) * AH + j];
        a3 += fr[k + 3] * w1[(k + 3) * AH + j];
    }
    h1ws[(size_t)g * AH + j] = fmaxf((a0 + a1) + (a2 + a3) + b1[j], 0.f);
}

// ---------------- MLP layer 2 (direct strided w2 reads) ----------------
__global__ __launch_bounds__(256) void k_mlp2(const float* __restrict__ h1ws,
                                              const float* __restrict__ w2,
                                              const float* __restrict__ b2,
                                              float* __restrict__ out_fea) {
    int f = blockIdx.x;
    int g = threadIdx.x >> 2, q = threadIdx.x & 3;
    const float* hr = h1ws + (size_t)g * AH + q * 128;
    const float* wr = w2 + (size_t)q * 128 * FEA + f;
    float a0 = 0.f, a1 = 0.f, a2 = 0.f, a3 = 0.f;
#pragma unroll 8
    for (int k = 0; k < 128; k += 4) {
        a0 += hr[k + 0] * wr[(k + 0) * FEA];
        a1 += hr[k + 1] * wr[(k + 1) * FEA];
        a2 += hr[k + 2] * wr[(k + 2) * FEA];
        a3 += hr[k + 3] * wr[(k + 3) * FEA];
    }
    float p = (a0 + a1) + (a2 + a3);
    p += __shfl_xor(p, 1);
    p += __shfl_xor(p, 2);
    if (q == 0) out_fea[(size_t)g * FEA + f] = p + b2[f];
}

extern "C" void kernel_launch(void* const* d_in, const int* in_sizes, int n_in,
                              void* d_out, int out_size, void* d_ws, size_t ws_size,
                              hipStream_t stream) {
    const float* x     = (const float*)d_in[0];
    const int*   ei    = (const int*)d_in[1];
    const int*   batch = (const int*)d_in[2];
    const float* convW = (const float*)d_in[3];
    const float* convb = (const float*)d_in[4];
    const float* w1    = (const float*)d_in[5];
    const float* b1    = (const float*)d_in[6];
    const float* w2    = (const float*)d_in[7];
    const float* b2    = (const float*)d_in[8];
    const float* nw    = (const float*)d_in[9];
    const float* nb    = (const float*)d_in[10];
    float* out = (float*)d_out;

    // workspace layout (4-byte word offsets)
    char* wsb = (char*)d_ws;
    int*    deg    = (int*)wsb;                        // 50000
    float*  dinv   = (float*)(wsb + 50048ll * 4);      // 50000
    int*    rowptr = (int*)(wsb + 100096ll * 4);       // 50001
    int*    bsum   = (int*)(wsb + 150144ll * 4);       // 196
    int*    boff   = (int*)(wsb + 150344ll * 4);       // 196
    int*    gstart = (int*)(wsb + 150544ll * 4);       // 65
    int*    rankw  = (int*)(wsb + 150656ll * 4);       // 400000 words
    ushort* rank   = (ushort*)rankw;                   // 800000 ushort
    float*  h1ws   = (float*)rankw;                    // 32768 w (after fill)
    ushort* eidx   = (ushort*)(wsb + 950656ll * 4);    // <=1.3M ushort
    ushort* H      = (ushort*)(wsb + 1600672ll * 4);   // 4*(N+1)*32 bf16
    ushort* Xhi    = (ushort*)(wsb + 4800736ll * 4);   // 4*N*32 bf16
    ushort* Xlo    = (ushort*)(wsb + 8000736ll * 4);   // 4*N*32 bf16
    float*  psum_part = (float*)(wsb + 11200736ll * 4);// 1024*128 floats
    // WhiT/WloT alias psum_part: dead after last gemm, psum written by k_pool later
    ushort* WhiT   = (ushort*)psum_part;               // 49152 shorts
    ushort* WloT   = WhiT + 49152;                     // 49152 shorts

    const int* srcp = ei;
    const int* dstp = ei + N_EDGES;

    // ---- CSR build + prep ----
    hipMemsetAsync(deg, 0, N_NODES * sizeof(int), stream);
    k_deg_prep<<<DD, 256, 0, stream>>>(dstp, deg, rank, x, Xhi, Xlo, convW, WhiT, WloT, H);
    k_scan1<<<NBLK, 256, 0, stream>>>(deg, rowptr, bsum, dinv);
    k_scan2<<<1, 256, 0, stream>>>(bsum, boff, rowptr);
    k_scan3<<<NBLK, 256, 0, stream>>>(rowptr, boff);
    k_fill2<<<FC, 256, 0, stream>>>(srcp, dstp, rowptr, rank, deg, batch, eidx, gstart);

    // ---- GCN layers ----
    for (int l = 0; l < NL; ++l) {
        k_gemm<<<1024, 256, 0, stream>>>(Xhi, Xlo, WhiT + (size_t)l * 16384,
                                         WloT + (size_t)l * 16384, dinv, H);
        k_gather<<<GNB * 4, 256, 0, stream>>>(
            rowptr, eidx, dinv, H, convb + (size_t)l * FEA, Xhi, Xlo);
    }

    // ---- heads ----
    k_pool<<<NG * 16, 256, 0, stream>>>(Xhi, Xlo, gstart, nw, nb, out, psum_part);
    k_mlp1<<<128, 256, 0, stream>>>(psum_part, gstart, w1, b1, h1ws);
    k_mlp2<<<128, 256, 0, stream>>>(h1ws, w2, b2, out + N_NODES);
}

// Round 15
// 225.613 us; speedup vs baseline: 1.7828x; 1.0942x over previous
//
#include <hip/hip_runtime.h>

#define N_NODES 50000
#define N_EDGES 800000
#define FEA 128
#define NL 3
#define AH 512
#define NG 64
#define NBLK 196   // ceil(50000/256)

typedef short bf16x8 __attribute__((ext_vector_type(8)));
typedef float f32x4 __attribute__((ext_vector_type(4)));
typedef uint  u32x4 __attribute__((ext_vector_type(4)));

__device__ __forceinline__ ushort f2bf(float f) {   // RTN-even
    uint u = __float_as_uint(f);
    uint r = u + 0x7FFFu + ((u >> 16) & 1u);
    return (ushort)(r >> 16);
}
__device__ __forceinline__ float bf2f(ushort u) {
    return __uint_as_float((uint)u << 16);
}

// Column-sliced layouts: 4 slices of 64B (32 bf16 features) per row.
//  H : 4 slices x [(N_NODES+1) rows][32 bf16]  (pad row at N_NODES)
//  X : 4 slices x [N_NODES rows][32 bf16]      (single bf16 plane)
#define HS ((size_t)(N_NODES + 1) * 32)   // ushorts per H slice
#define XS ((size_t)N_NODES * 32)         // ushorts per X slice

// ---------------- fused: degree+rank | x->Xcs | convW split-T | H pad rows ----------------
#define DA 3125            // deg blocks (3125*256 = 800000 edges)
#define DB (DA + 3125)     // x conversion: 800000 8-feature chunks
#define DC (DB + 192)      // conv W split-transpose (3*16384)
#define DD (DC + 1)        // pad row zero
__global__ __launch_bounds__(256) void k_deg_prep(const int* __restrict__ dst,
                                                  int* __restrict__ deg,
                                                  ushort* __restrict__ rank,
                                                  const float* __restrict__ x,
                                                  ushort* __restrict__ X,
                                                  const float* __restrict__ convW,
                                                  ushort* __restrict__ WhiT,
                                                  ushort* __restrict__ WloT,
                                                  ushort* __restrict__ H) {
    int blk = blockIdx.x;
    if (blk < DA) {                        // degree histogram + rank
        int i = blk * 256 + threadIdx.x;
        rank[i] = (ushort)atomicAdd(&deg[dst[i]], 1);
    } else if (blk < DB) {                 // x -> column-sliced X bf16 (8 floats/thread)
        int i = (blk - DA) * 256 + threadIdx.x;   // chunk id, 0..799999
        int node = i >> 4, c8 = i & 15;           // features c8*8 .. c8*8+7
        const float* xr = x + (size_t)node * FEA + c8 * 8;
        float4 u0 = *(const float4*)xr;
        float4 u1 = *(const float4*)(xr + 4);
        float xs[8] = {u0.x, u0.y, u0.z, u0.w, u1.x, u1.y, u1.z, u1.w};
        ushort hs[8];
#pragma unroll
        for (int k = 0; k < 8; ++k) hs[k] = f2bf(xs[k]);
        u32x4 hv;
        hv.x = (uint)hs[0] | ((uint)hs[1] << 16);
        hv.y = (uint)hs[2] | ((uint)hs[3] << 16);
        hv.z = (uint)hs[4] | ((uint)hs[5] << 16);
        hv.w = (uint)hs[6] | ((uint)hs[7] << 16);
        *(u32x4*)(X + (size_t)(c8 >> 2) * XS + (size_t)node * 32 + (c8 & 3) * 8) = hv;
    } else if (blk < DC) {                 // conv W split-transpose
        int t = (blk - DB) * 256 + threadIdx.x;     // 0..49151
        int l = t >> 14, r = t & 16383;
        int k = r >> 7, c = r & 127;
        float w = convW[t];
        ushort h = f2bf(w);
        WhiT[(size_t)l * 16384 + c * FEA + k] = h;
        WloT[(size_t)l * 16384 + c * FEA + k] = f2bf(w - bf2f(h));
    } else {                               // zero H pad rows (4 slices x 64B)
        if (threadIdx.x < 64) {
            int c = threadIdx.x >> 4, j = threadIdx.x & 15;
            ((uint*)H)[(size_t)c * (HS / 2) + (size_t)N_NODES * 16 + j] = 0;
        }
    }
}

// ---------------- 3-kernel exclusive scan over PADDED degrees ----------------
__device__ __forceinline__ int block_scan_incl(int v, int* wsum) {
    int lane = threadIdx.x & 63, w = threadIdx.x >> 6;
    int s = v;
#pragma unroll
    for (int off = 1; off < 64; off <<= 1) {
        int t = __shfl_up(s, off);
        if (lane >= off) s += t;
    }
    if (lane == 63) wsum[w] = s;
    __syncthreads();
    int woff = 0;
    for (int k = 0; k < w; ++k) woff += wsum[k];
    return woff + s;  // block-wide inclusive
}

__global__ __launch_bounds__(256) void k_scan1(const int* __restrict__ deg,
                                               int* __restrict__ rowptr,
                                               int* __restrict__ bsum,
                                               float* __restrict__ dinv) {
    __shared__ int wsum[4];
    int i = blockIdx.x * 256 + threadIdx.x;
    int v = (i < N_NODES) ? deg[i] : 0;
    int pv = (v + 7) & ~7;                       // pad to multiple of 8
    int incl = block_scan_incl(pv, wsum);
    if (i < N_NODES) {
        rowptr[i] = incl - pv;                   // local exclusive
        dinv[i] = rsqrtf((float)v + 1.0f);
    }
    if (threadIdx.x == 255) bsum[blockIdx.x] = incl;
}

__global__ __launch_bounds__(256) void k_scan2(int* __restrict__ bsum,
                                               int* __restrict__ boff,
                                               int* __restrict__ rowptr) {
    __shared__ int wsum[4];
    int v = (threadIdx.x < NBLK) ? bsum[threadIdx.x] : 0;
    int incl = block_scan_incl(v, wsum);
    if (threadIdx.x < NBLK) boff[threadIdx.x] = incl - v;
    if (threadIdx.x == NBLK - 1) rowptr[N_NODES] = incl;  // total padded edges
}

__global__ __launch_bounds__(256) void k_scan3(int* __restrict__ rowptr,
                                               const int* __restrict__ boff) {
    int i = blockIdx.x * 256 + threadIdx.x;
    if (i < N_NODES) rowptr[i] += boff[blockIdx.x];
}

// ---------------- fused: CSR fill | pad slots | graph bounds ----------------
#define FA 3125
#define FB (FA + NBLK)
#define FC (FB + NBLK)
__global__ __launch_bounds__(256) void k_fill2(const int* __restrict__ src,
                                               const int* __restrict__ dst,
                                               const int* __restrict__ rowptr,
                                               const ushort* __restrict__ rank,
                                               const int* __restrict__ deg,
                                               const int* __restrict__ batch,
                                               ushort* __restrict__ eidx,
                                               int* __restrict__ gstart) {
    int blk = blockIdx.x;
    if (blk < FA) {                        // CSR fill (no atomics)
        int e = blk * 256 + threadIdx.x;
        eidx[rowptr[dst[e]] + (int)rank[e]] = (ushort)src[e];
    } else if (blk < FB) {                 // pad slots -> zero row
        int i = (blk - FA) * 256 + threadIdx.x;
        if (i < N_NODES) {
            int d = deg[i], r = rowptr[i];
            int pd = (d + 7) & ~7;
            for (int k = d; k < pd; ++k) eidx[r + k] = (ushort)N_NODES;
        }
    } else {                               // graph bounds from sorted batch
        int i = (blk - FB) * 256 + threadIdx.x;
        if (i < N_NODES) {
            int b = batch[i];
            int bp = (i == 0) ? -1 : batch[i - 1];
            for (int g = bp + 1; g <= b; ++g) gstart[g] = i;
            if (i == N_NODES - 1)
                for (int g = b + 1; g <= NG; ++g) gstart[g] = N_NODES;
        }
    }
}

// ---------------- MFMA GEMM: H'cs(bf16) = dinv * (Xcs @ (Whi+Wlo)) ----------------
__global__ __launch_bounds__(256) void k_gemm(const ushort* __restrict__ X,
                                              const ushort* __restrict__ WhiT,
                                              const ushort* __restrict__ WloT,
                                              const float* __restrict__ dinv,
                                              ushort* __restrict__ H) {
    const int wv = threadIdx.x >> 6;
    const int lane = threadIdx.x & 63;
    const int lr = lane & 15;
    const int lk = lane >> 4;

    bf16x8 bhi[2][4], blo[2][4];
#pragma unroll
    for (int ct = 0; ct < 2; ++ct) {
        int col = wv * 32 + ct * 16 + lr;
#pragma unroll
        for (int kf = 0; kf < 4; ++kf) {
            bhi[ct][kf] = *(const bf16x8*)(WhiT + (size_t)col * FEA + kf * 32 + lk * 8);
            blo[ct][kf] = *(const bf16x8*)(WloT + (size_t)col * FEA + kf * 32 + lk * 8);
        }
    }

    for (int rt = blockIdx.x; rt < N_NODES / 16; rt += gridDim.x) {
        int r0 = rt * 16;
        bf16x8 a[4];
#pragma unroll
        for (int kf = 0; kf < 4; ++kf) {
            // features kf*32 + lk*8 -> slice kf, intra lk*8
            a[kf] = *(const bf16x8*)(X + (size_t)kf * XS + (size_t)(r0 + lr) * 32 + lk * 8);
        }
        f32x4 acc0 = {0.f, 0.f, 0.f, 0.f};
        f32x4 acc1 = {0.f, 0.f, 0.f, 0.f};
#pragma unroll
        for (int kf = 0; kf < 4; ++kf) {
            acc0 = __builtin_amdgcn_mfma_f32_16x16x32_bf16(a[kf], bhi[0][kf], acc0, 0, 0, 0);
            acc0 = __builtin_amdgcn_mfma_f32_16x16x32_bf16(a[kf], blo[0][kf], acc0, 0, 0, 0);
            acc1 = __builtin_amdgcn_mfma_f32_16x16x32_bf16(a[kf], bhi[1][kf], acc1, 0, 0, 0);
            acc1 = __builtin_amdgcn_mfma_f32_16x16x32_bf16(a[kf], blo[1][kf], acc1, 0, 0, 0);
        }
        // cols wv*32 + lr (acc0) and wv*32 + 16 + lr (acc1) -> slice wv
#pragma unroll
        for (int reg = 0; reg < 4; ++reg) {
            int orow = r0 + lk * 4 + reg;
            float s = dinv[orow];
            H[(size_t)wv * HS + (size_t)orow * 32 + lr]      = f2bf(acc0[reg] * s);
            H[(size_t)wv * HS + (size_t)orow * 32 + 16 + lr] = f2bf(acc1[reg] * s);
        }
    }
}

// ---------------- gather: 4 lanes/node x one 64B slice; c = blk&3 -> XCD-local ----------------
#define GNPB 64    // nodes per block
#define GNB ((N_NODES + GNPB - 1) / GNPB)
__global__ __launch_bounds__(256) void k_gather(const int* __restrict__ rowptr,
                                                const ushort* __restrict__ eidx,
                                                const float* __restrict__ dinv,
                                                const ushort* __restrict__ H,
                                                const float* __restrict__ b,
                                                ushort* __restrict__ X) {
    int c = blockIdx.x & 3;
    int node = (blockIdx.x >> 2) * GNPB + (threadIdx.x >> 2);
    int l4 = threadIdx.x & 3;              // uint4 offset within 64B slice row
    if (node >= N_NODES) return;
    const uint4* Hs = (const uint4*)H + (size_t)c * (N_NODES + 1) * 4;
    int r0 = rowptr[node], r1 = rowptr[node + 1];

    float a[8] = {0.f, 0.f, 0.f, 0.f, 0.f, 0.f, 0.f, 0.f};
#define ACC8(u)                                                              \
    do {                                                                     \
        a[0] += __uint_as_float((u).x << 16);                                \
        a[1] += __uint_as_float((u).x & 0xffff0000u);                        \
        a[2] += __uint_as_float((u).y << 16);                                \
        a[3] += __uint_as_float((u).y & 0xffff0000u);                        \
        a[4] += __uint_as_float((u).z << 16);                                \
        a[5] += __uint_as_float((u).z & 0xffff0000u);                        \
        a[6] += __uint_as_float((u).w << 16);                                \
        a[7] += __uint_as_float((u).w & 0xffff0000u);                        \
    } while (0)

    uint4 sv = Hs[(size_t)node * 4 + l4];  // self term
    ACC8(sv);

    for (int j = r0; j < r1; j += 8) {     // j 8-aligned -> 16B-aligned
        uint4 ev = *(const uint4*)(eidx + j);   // same addr across node's 4 lanes
        int s0 = ev.x & 0xffff, s1 = ev.x >> 16;
        int s2 = ev.y & 0xffff, s3 = ev.y >> 16;
        int s4 = ev.z & 0xffff, s5 = ev.z >> 16;
        int s6 = ev.w & 0xffff, s7 = ev.w >> 16;
        uint4 h0 = Hs[(size_t)s0 * 4 + l4];
        uint4 h1 = Hs[(size_t)s1 * 4 + l4];
        uint4 h2 = Hs[(size_t)s2 * 4 + l4];
        uint4 h3 = Hs[(size_t)s3 * 4 + l4];
        uint4 h4 = Hs[(size_t)s4 * 4 + l4];
        uint4 h5 = Hs[(size_t)s5 * 4 + l4];
        uint4 h6 = Hs[(size_t)s6 * 4 + l4];
        uint4 h7 = Hs[(size_t)s7 * 4 + l4];
        ACC8(h0); ACC8(h1); ACC8(h2); ACC8(h3);
        ACC8(h4); ACC8(h5); ACC8(h6); ACC8(h7);
    }
#undef ACC8

    float di = dinv[node];
    const float4* b4 = (const float4*)(b + c * 32 + l4 * 8);
    float4 bb0 = b4[0], bb1 = b4[1];
    float o[8];
    o[0] = fmaxf(a[0] * di + bb0.x, 0.f);
    o[1] = fmaxf(a[1] * di + bb0.y, 0.f);
    o[2] = fmaxf(a[2] * di + bb0.z, 0.f);
    o[3] = fmaxf(a[3] * di + bb0.w, 0.f);
    o[4] = fmaxf(a[4] * di + bb1.x, 0.f);
    o[5] = fmaxf(a[5] * di + bb1.y, 0.f);
    o[6] = fmaxf(a[6] * di + bb1.z, 0.f);
    o[7] = fmaxf(a[7] * di + bb1.w, 0.f);

    ushort hs[8];
#pragma unroll
    for (int i = 0; i < 8; ++i) hs[i] = f2bf(o[i]);
    u32x4 hv;
    hv.x = (uint)hs[0] | ((uint)hs[1] << 16);
    hv.y = (uint)hs[2] | ((uint)hs[3] << 16);
    hv.z = (uint)hs[4] | ((uint)hs[5] << 16);
    hv.w = (uint)hs[6] | ((uint)hs[7] << 16);
    __builtin_nontemporal_store(hv, (u32x4*)(X + (size_t)c * XS + (size_t)node * 32 + l4 * 8));
}

// ---------------- pool + node head (no atomics), 16 partials/graph ----------------
__global__ __launch_bounds__(256) void k_pool(const ushort* __restrict__ X,
                                              const int* __restrict__ gstart,
                                              const float* __restrict__ nw,
                                              const float* __restrict__ nbp,
                                              float* __restrict__ out_node,
                                              float* __restrict__ psum_part) {
    int g = blockIdx.x >> 4, p = blockIdx.x & 15;
    int s = gstart[g], e = gstart[g + 1];
    int len = e - s;
    int lp = (len + 15) >> 4;
    int ps = s + p * lp, pe = min(ps + lp, e);
    int q = threadIdx.x >> 6, lane = threadIdx.x & 63;
    // lane l holds features 2l,2l+1: uint idx l -> slice l>>4, intra l&15
    const uint* hb = (const uint*)X + (size_t)(lane >> 4) * (XS / 2) + (lane & 15);
    float2 w = ((const float2*)nw)[lane];
    float nbv = nbp[0];
    float2 acc = {0.f, 0.f};
    for (int node = ps + q; node < pe; node += 4) {
        uint hv = hb[(size_t)node * 16];
        float2 v;
        v.x = bf2f((ushort)hv);
        v.y = bf2f((ushort)(hv >> 16));
        acc.x += v.x; acc.y += v.y;
        float dot = v.x * w.x + v.y * w.y;
#pragma unroll
        for (int off = 32; off; off >>= 1) dot += __shfl_down(dot, off);
        if (lane == 0) out_node[node] = dot + nbv;
    }
    __shared__ float lds[4 * FEA];
    lds[q * FEA + lane * 2 + 0] = acc.x;
    lds[q * FEA + lane * 2 + 1] = acc.y;
    __syncthreads();
    if (threadIdx.x < FEA) {
        psum_part[(size_t)blockIdx.x * FEA + threadIdx.x] =
            lds[threadIdx.x] + lds[FEA + threadIdx.x] +
            lds[2 * FEA + threadIdx.x] + lds[3 * FEA + threadIdx.x];
    }
}

// ---------------- MLP layer 1 (direct strided w1 reads) ----------------
__global__ __launch_bounds__(256) void k_mlp1(const float* __restrict__ psum_part,
                                              const int* __restrict__ gstart,
                                              const float* __restrict__ w1,
                                              const float* __restrict__ b1,
                                              float* __restrict__ h1ws) {
    __shared__ float feas[NG * 132];   // pad 132 to spread banks
    for (int idx = threadIdx.x; idx < NG * FEA; idx += 256) {
        int g = idx >> 7, f = idx & 127;
        const float* pp = psum_part + (size_t)g * 16 * FEA + f;
        float sum = 0.f;
#pragma unroll
        for (int p = 0; p < 16; ++p) sum += pp[p * FEA];
        float cnt = fmaxf((float)(gstart[g + 1] - gstart[g]), 1.0f);
        feas[g * 132 + f] = sum / cnt;
    }
    __syncthreads();
    int g = threadIdx.x >> 2, jj = threadIdx.x & 3;
    int j = blockIdx.x * 4 + jj;
    const float* fr = feas + g * 132;
    float a0 = 0.f, a1 = 0.f, a2 = 0.f, a3 = 0.f;
#pragma unroll 8
    for (int k = 0; k < FEA; k += 4) {
        a0 += fr[k + 0] * w1[(k + 0) * AH + j];
        a1 += fr[k + 1] * w1[(k + 1) * AH + j];
        a2 += fr[k + 2] * w1[(k + 2) * AH + j];
        a3 += fr[k + 3] * w1[(k + 3) * AH + j];
    }
    h1ws[(size_t)g * AH + j] = fmaxf((a0 + a1) + (a2 + a3) + b1[j], 0.f);
}

// ---------------- MLP layer 2 (direct strided w2 reads) ----------------
__global__ __launch_bounds__(256) void k_mlp2(const float* __restrict__ h1ws,
                                              const float* __restrict__ w2,
                                              const float* __restrict__ b2,
                                              float* __restrict__ out_fea) {
    int f = blockIdx.x;
    int g = threadIdx.x >> 2, q = threadIdx.x & 3;
    const float* hr = h1ws + (size_t)g * AH + q * 128;
    const float* wr = w2 + (size_t)q * 128 * FEA + f;
    float a0 = 0.f, a1 = 0.f, a2 = 0.f, a3 = 0.f;
#pragma unroll 8
    for (int k = 0; k < 128; k += 4) {
        a0 += hr[k + 0] * wr[(k + 0) * FEA];
        a1 += hr[k + 1] * wr[(k + 1) * FEA];
        a2 += hr[k + 2] * wr[(k + 2) * FEA];
        a3 += hr[k + 3] * wr[(k + 3) * FEA];
    }
    float p = (a0 + a1) + (a2 + a3);
    p += __shfl_xor(p, 1);
    p += __shfl_xor(p, 2);
    if (q == 0) out_fea[(size_t)g * FEA + f] = p + b2[f];
}

extern "C" void kernel_launch(void* const* d_in, const int* in_sizes, int n_in,
                              void* d_out, int out_size, void* d_ws, size_t ws_size,
                              hipStream_t stream) {
    const float* x     = (const float*)d_in[0];
    const int*   ei    = (const int*)d_in[1];
    const int*   batch = (const int*)d_in[2];
    const float* convW = (const float*)d_in[3];
    const float* convb = (const float*)d_in[4];
    const float* w1    = (const float*)d_in[5];
    const float* b1    = (const float*)d_in[6];
    const float* w2    = (const float*)d_in[7];
    const float* b2    = (const float*)d_in[8];
    const float* nw    = (const float*)d_in[9];
    const float* nb    = (const float*)d_in[10];
    float* out = (float*)d_out;

    // workspace layout (4-byte word offsets)
    char* wsb = (char*)d_ws;
    int*    deg    = (int*)wsb;                        // 50000
    float*  dinv   = (float*)(wsb + 50048ll * 4);      // 50000
    int*    rowptr = (int*)(wsb + 100096ll * 4);       // 50001
    int*    bsum   = (int*)(wsb + 150144ll * 4);       // 196
    int*    boff   = (int*)(wsb + 150344ll * 4);       // 196
    int*    gstart = (int*)(wsb + 150544ll * 4);       // 65
    int*    rankw  = (int*)(wsb + 150656ll * 4);       // 400000 words
    ushort* rank   = (ushort*)rankw;                   // 800000 ushort
    float*  h1ws   = (float*)rankw;                    // 32768 w (after fill)
    ushort* eidx   = (ushort*)(wsb + 950656ll * 4);    // <=1.3M ushort
    ushort* H      = (ushort*)(wsb + 1600672ll * 4);   // 4*(N+1)*32 bf16
    ushort* X      = (ushort*)(wsb + 4800736ll * 4);   // 4*N*32 bf16
    float*  psum_part = (float*)(wsb + 11200736ll * 4);// 1024*128 floats
    // WhiT/WloT alias psum_part: dead after last gemm, psum written by k_pool later
    ushort* WhiT   = (ushort*)psum_part;               // 49152 shorts
    ushort* WloT   = WhiT + 49152;                     // 49152 shorts

    const int* srcp = ei;
    const int* dstp = ei + N_EDGES;

    // ---- CSR build + prep ----
    hipMemsetAsync(deg, 0, N_NODES * sizeof(int), stream);
    k_deg_prep<<<DD, 256, 0, stream>>>(dstp, deg, rank, x, X, convW, WhiT, WloT, H);
    k_scan1<<<NBLK, 256, 0, stream>>>(deg, rowptr, bsum, dinv);
    k_scan2<<<1, 256, 0, stream>>>(bsum, boff, rowptr);
    k_scan3<<<NBLK, 256, 0, stream>>>(rowptr, boff);
    k_fill2<<<FC, 256, 0, stream>>>(srcp, dstp, rowptr, rank, deg, batch, eidx, gstart);

    // ---- GCN layers ----
    for (int l = 0; l < NL; ++l) {
        k_gemm<<<1024, 256, 0, stream>>>(X, WhiT + (size_t)l * 16384,
                                         WloT + (size_t)l * 16384, dinv, H);
        k_gather<<<GNB * 4, 256, 0, stream>>>(
            rowptr, eidx, dinv, H, convb + (size_t)l * FEA, X);
    }

    // ---- heads ----
    k_pool<<<NG * 16, 256, 0, stream>>>(X, gstart, nw, nb, out, psum_part);
    k_mlp1<<<128, 256, 0, stream>>>(psum_part, gstart, w1, b1, h1ws);
    k_mlp2<<<128, 256, 0, stream>>>(h1ws, w2, b2, out + N_NODES);
}